// Round 1
// baseline (1425.311 us; speedup 1.0000x reference)
//
#include <hip/hip_runtime.h>
#include <hip/hip_bf16.h>
#include <stdint.h>

#define D_MODEL 1024
#define QKV_LD  3072
#define N_TOT   9860
#define M_PAD   9984   // 78*128
#define LN_EPS  1e-5f

typedef __bf16 bf16_t;
typedef __bf16 bf16x8 __attribute__((ext_vector_type(8)));
typedef float  f32x4  __attribute__((ext_vector_type(4)));

__device__ inline unsigned short f2bf(float f) {
  __bf16 h = (__bf16)f;
  return __builtin_bit_cast(unsigned short, h);
}

// ---------------- weight f32 -> bf16 ----------------
__global__ __launch_bounds__(256) void cvt_f32_bf16(const float* __restrict__ src,
                                                    bf16_t* __restrict__ dst, int n4) {
  int i = blockIdx.x * 256 + threadIdx.x;
  if (i < n4) {
    float4 v = ((const float4*)src)[i];
    ((ushort4*)dst)[i] = make_ushort4(f2bf(v.x), f2bf(v.y), f2bf(v.z), f2bf(v.w));
  }
}

// ---------------- LayerNorm: x f32 -> h bf16 (pads zeroed) ----------------
__global__ __launch_bounds__(256) void ln_kernel(const float* __restrict__ x,
                                                 const float* __restrict__ g,
                                                 const float* __restrict__ b,
                                                 bf16_t* __restrict__ hout,
                                                 bf16_t* __restrict__ opad) {
  int row = blockIdx.x;
  int t = threadIdx.x;
  if (row >= N_TOT) {
    ((ushort4*)(hout + (size_t)row * D_MODEL))[t] = make_ushort4(0, 0, 0, 0);
    ((ushort4*)(opad + (size_t)row * D_MODEL))[t] = make_ushort4(0, 0, 0, 0);
    return;
  }
  float4 v = ((const float4*)(x + (size_t)row * D_MODEL))[t];
  float s  = v.x + v.y + v.z + v.w;
  float sq = v.x * v.x + v.y * v.y + v.z * v.z + v.w * v.w;
  #pragma unroll
  for (int off = 1; off < 64; off <<= 1) {
    s  += __shfl_xor(s, off);
    sq += __shfl_xor(sq, off);
  }
  __shared__ float ss[4], ssq[4];
  int wid = t >> 6;
  if ((t & 63) == 0) { ss[wid] = s; ssq[wid] = sq; }
  __syncthreads();
  s  = ss[0] + ss[1] + ss[2] + ss[3];
  sq = ssq[0] + ssq[1] + ssq[2] + ssq[3];
  float mu  = s * (1.0f / 1024.0f);
  float var = sq * (1.0f / 1024.0f) - mu * mu;
  float rs  = rsqrtf(var + LN_EPS);
  float4 gv = ((const float4*)g)[t];
  float4 bv = ((const float4*)b)[t];
  ushort4 o;
  o.x = f2bf((v.x - mu) * rs * gv.x + bv.x);
  o.y = f2bf((v.y - mu) * rs * gv.y + bv.y);
  o.z = f2bf((v.z - mu) * rs * gv.z + bv.z);
  o.w = f2bf((v.w - mu) * rs * gv.w + bv.w);
  ((ushort4*)(hout + (size_t)row * D_MODEL))[t] = o;
}

// ---------------- GEMM: C[M][NC] = A[M][K] * B[NC][K]^T (+bias, +resid) ----------------
// 128x128 tile, BK=64, 256 threads = 2x2 waves, XOR-swizzled LDS, mfma 16x16x32 bf16
template<int NCOLS, bool FINAL>
__global__ __launch_bounds__(256) void gemm_bt(const bf16_t* __restrict__ A,
                                               const bf16_t* __restrict__ B,
                                               const float* __restrict__ bias,
                                               bf16_t* __restrict__ Cbf,
                                               float* __restrict__ Cf,
                                               const float* __restrict__ resid) {
  constexpr int K = 1024;
  const int tileM = blockIdx.x;
  const int tileN = blockIdx.y;
  const int t = threadIdx.x;
  const int lane = t & 63, wid = t >> 6;
  const int wr = wid >> 1, wc = wid & 1;

  __shared__ bf16_t Asm[128 * 64];
  __shared__ bf16_t Bsm[128 * 64];

  f32x4 acc[4][4];
  #pragma unroll
  for (int m = 0; m < 4; ++m)
    #pragma unroll
    for (int n = 0; n < 4; ++n)
      acc[m][n] = f32x4{0.f, 0.f, 0.f, 0.f};

  const int rowA0 = tileM * 128, rowB0 = tileN * 128;

  for (int kt = 0; kt < K / 64; ++kt) {
    __syncthreads();
    const int k0 = kt * 64;
    #pragma unroll
    for (int i = 0; i < 4; ++i) {
      int idx = i * 256 + t;
      int r = idx >> 3, c = idx & 7;
      int sw = (c ^ (r & 7)) * 16;
      int4 va = *(const int4*)(A + (size_t)(rowA0 + r) * K + k0 + c * 8);
      *(int4*)((char*)Asm + r * 128 + sw) = va;
      int4 vb = *(const int4*)(B + (size_t)(rowB0 + r) * K + k0 + c * 8);
      *(int4*)((char*)Bsm + r * 128 + sw) = vb;
    }
    __syncthreads();
    #pragma unroll
    for (int ks = 0; ks < 2; ++ks) {
      bf16x8 af[4], bfr[4];
      #pragma unroll
      for (int m = 0; m < 4; ++m) {
        int r = wr * 64 + m * 16 + (lane & 15);
        int c = ks * 4 + (lane >> 4);
        af[m] = *(const bf16x8*)((const char*)Asm + r * 128 + ((c ^ (r & 7)) * 16));
      }
      #pragma unroll
      for (int n = 0; n < 4; ++n) {
        int r = wc * 64 + n * 16 + (lane & 15);
        int c = ks * 4 + (lane >> 4);
        bfr[n] = *(const bf16x8*)((const char*)Bsm + r * 128 + ((c ^ (r & 7)) * 16));
      }
      #pragma unroll
      for (int m = 0; m < 4; ++m)
        #pragma unroll
        for (int n = 0; n < 4; ++n)
          acc[m][n] = __builtin_amdgcn_mfma_f32_16x16x32_bf16(af[m], bfr[n], acc[m][n], 0, 0, 0);
    }
  }

  #pragma unroll
  for (int m = 0; m < 4; ++m) {
    int rb = tileM * 128 + wr * 64 + m * 16 + ((lane >> 4) << 2);
    #pragma unroll
    for (int n = 0; n < 4; ++n) {
      int cb = tileN * 128 + wc * 64 + n * 16 + (lane & 15);
      float bv = bias[cb];
      #pragma unroll
      for (int j = 0; j < 4; ++j) {
        int grow = rb + j;
        float val = acc[m][n][j] + bv;
        if constexpr (FINAL) {
          if (grow < N_TOT) {
            size_t idx = (size_t)grow * NCOLS + cb;
            Cf[idx] = resid[idx] + val;
          }
        } else {
          Cbf[(size_t)grow * NCOLS + cb] = (bf16_t)val;
        }
      }
    }
  }
}

// ---------------- attention: flash-style, VALU f32 (correctness-first) ----------------
// block = 256 threads, handles 64 q rows of one (batch, head); K/V tiles of 64 in LDS
__global__ __launch_bounds__(256) void attn_kernel(const bf16_t* __restrict__ qkv,
                                                   bf16_t* __restrict__ obuf) {
  static const int off_[9] = {0, 1536, 2560, 3960, 4860, 6060, 7360, 8860, 9860};
  static const int ts_[9]  = {0, 24, 40, 62, 77, 96, 117, 141, 157};

  const int tt = blockIdx.x;
  const int h  = blockIdx.y;
  int b = 0;
  #pragma unroll
  for (int i = 1; i < 8; ++i) b += (tt >= ts_[i]);
  const int L    = off_[b + 1] - off_[b];
  const int q0l  = (tt - ts_[b]) * 64;
  const int tok0 = off_[b] + q0l;
  const int nq   = (L - q0l < 64) ? (L - q0l) : 64;

  const int t = threadIdx.x;
  const int r = t >> 2, g = t & 3;

  __shared__ float Ksm[64][68];
  __shared__ float Vsm[64][68];
  __shared__ float Psm[64][65];

  // q row r into registers (pre-scaled by 1/sqrt(64)); rows >= nq give discarded output
  float q[64];
  {
    const bf16_t* qp = qkv + (size_t)(tok0 + r) * QKV_LD + h * 64;
    #pragma unroll
    for (int d8 = 0; d8 < 8; ++d8) {
      bf16x8 vv = *(const bf16x8*)(qp + d8 * 8);
      #pragma unroll
      for (int j = 0; j < 8; ++j) q[d8 * 8 + j] = (float)vv[j] * 0.125f;
    }
  }

  float o[16];
  #pragma unroll
  for (int i = 0; i < 16; ++i) o[i] = 0.f;
  float mrun = -INFINITY, lrun = 0.f;

  for (int kv0 = 0; kv0 < L; kv0 += 64) {
    const int nk = (L - kv0 < 64) ? (L - kv0) : 64;
    __syncthreads();  // previous tile's PV reads done
    // stage K/V tile: thread (r,g) loads key row j=r, dims g*16..g*16+15
    {
      const int j = r;
      if (j < nk) {
        const size_t ktok = (size_t)(off_[b] + kv0 + j);
        const bf16_t* kp = qkv + ktok * QKV_LD + 1024 + h * 64 + g * 16;
        const bf16_t* vp = qkv + ktok * QKV_LD + 2048 + h * 64 + g * 16;
        bf16x8 k0v = *(const bf16x8*)kp;
        bf16x8 k1v = *(const bf16x8*)(kp + 8);
        bf16x8 v0v = *(const bf16x8*)vp;
        bf16x8 v1v = *(const bf16x8*)(vp + 8);
        #pragma unroll
        for (int i = 0; i < 8; ++i) {
          Ksm[j][g * 16 + i]     = (float)k0v[i];
          Ksm[j][g * 16 + 8 + i] = (float)k1v[i];
          Vsm[j][g * 16 + i]     = (float)v0v[i];
          Vsm[j][g * 16 + 8 + i] = (float)v1v[i];
        }
      } else {
        #pragma unroll
        for (int i = 0; i < 16; ++i) {
          Ksm[j][g * 16 + i] = 0.f;
          Vsm[j][g * 16 + i] = 0.f;
        }
      }
    }
    __syncthreads();

    // S phase: thread (r,g) computes scores for keys j = g + 4*jj
    float p[16];
    float lmax = -INFINITY;
    #pragma unroll
    for (int jj = 0; jj < 16; ++jj) {
      const int j = g + (jj << 2);
      float s = 0.f;
      #pragma unroll
      for (int d4 = 0; d4 < 16; ++d4) {
        float4 kv = *(const float4*)(&Ksm[j][d4 * 4]);
        s += q[d4 * 4 + 0] * kv.x + q[d4 * 4 + 1] * kv.y +
             q[d4 * 4 + 2] * kv.z + q[d4 * 4 + 3] * kv.w;
      }
      if (j >= nk) s = -INFINITY;
      p[jj] = s;
      lmax = fmaxf(lmax, s);
    }
    lmax = fmaxf(lmax, __shfl_xor(lmax, 1));
    lmax = fmaxf(lmax, __shfl_xor(lmax, 2));
    const float mnew  = fmaxf(mrun, lmax);
    const float scale = __expf(mrun - mnew);
    float psum = 0.f;
    #pragma unroll
    for (int jj = 0; jj < 16; ++jj) {
      float pv = __expf(p[jj] - mnew);  // -inf -> 0
      p[jj] = pv;
      psum += pv;
      Psm[r][g + (jj << 2)] = pv;
    }
    psum += __shfl_xor(psum, 1);
    psum += __shfl_xor(psum, 2);
    lrun = lrun * scale + psum;
    mrun = mnew;
    #pragma unroll
    for (int i = 0; i < 16; ++i) o[i] *= scale;
    // P row r written+read by same wave only -> no barrier needed; V synced above

    // PV phase: thread (r,g) accumulates dims g*16..g*16+15
    for (int j = 0; j < 64; ++j) {
      float pv = Psm[r][j];
      #pragma unroll
      for (int d4 = 0; d4 < 4; ++d4) {
        float4 v = *(const float4*)(&Vsm[j][g * 16 + d4 * 4]);
        o[d4 * 4 + 0] += pv * v.x;
        o[d4 * 4 + 1] += pv * v.y;
        o[d4 * 4 + 2] += pv * v.z;
        o[d4 * 4 + 3] += pv * v.w;
      }
    }
  }

  if (r < nq) {
    const float inv = 1.f / lrun;
    bf16_t* op = obuf + (size_t)(tok0 + r) * D_MODEL + h * 64 + g * 16;
    unsigned short us[16];
    #pragma unroll
    for (int i = 0; i < 16; ++i) us[i] = f2bf(o[i] * inv);
    #pragma unroll
    for (int w4 = 0; w4 < 4; ++w4)
      ((ushort4*)op)[w4] = make_ushort4(us[4 * w4], us[4 * w4 + 1], us[4 * w4 + 2], us[4 * w4 + 3]);
  }
}

// ---------------- launcher ----------------
extern "C" void kernel_launch(void* const* d_in, const int* in_sizes, int n_in,
                              void* d_out, int out_size, void* d_ws, size_t ws_size,
                              hipStream_t stream) {
  const float* x     = (const float*)d_in[0];
  const float* w_in  = (const float*)d_in[2];
  const float* b_in  = (const float*)d_in[3];
  const float* w_out = (const float*)d_in[4];
  const float* b_out = (const float*)d_in[5];
  const float* ln_g  = (const float*)d_in[6];
  const float* ln_b  = (const float*)d_in[7];
  float* out = (float*)d_out;

  char* ws = (char*)d_ws;
  const size_t SZ_H   = (size_t)M_PAD * D_MODEL * 2;   // 20,447,232
  const size_t SZ_QKV = (size_t)M_PAD * QKV_LD * 2;    // 61,341,696
  const size_t SZ_O   = SZ_H;
  const size_t SZ_WIN = (size_t)QKV_LD * D_MODEL * 2;  // 6,291,456
  const size_t SZ_WO  = (size_t)D_MODEL * D_MODEL * 2; // 2,097,152
  if (ws_size < SZ_H + SZ_QKV + SZ_O + SZ_WIN + SZ_WO) return;

  bf16_t* h_bf    = (bf16_t*)ws;
  bf16_t* qkv_bf  = (bf16_t*)(ws + SZ_H);
  bf16_t* o_bf    = (bf16_t*)(ws + SZ_H + SZ_QKV);
  bf16_t* win_bf  = (bf16_t*)(ws + SZ_H + SZ_QKV + SZ_O);
  bf16_t* wout_bf = (bf16_t*)(ws + SZ_H + SZ_QKV + SZ_O + SZ_WIN);

  cvt_f32_bf16<<<(QKV_LD * D_MODEL / 4) / 256, 256, 0, stream>>>(w_in, win_bf, QKV_LD * D_MODEL / 4);
  cvt_f32_bf16<<<(D_MODEL * D_MODEL / 4) / 256, 256, 0, stream>>>(w_out, wout_bf, D_MODEL * D_MODEL / 4);

  ln_kernel<<<M_PAD, 256, 0, stream>>>(x, ln_g, ln_b, h_bf, o_bf);

  gemm_bt<QKV_LD, false><<<dim3(M_PAD / 128, QKV_LD / 128), 256, 0, stream>>>(
      h_bf, win_bf, b_in, qkv_bf, nullptr, nullptr);

  attn_kernel<<<dim3(157, 16), 256, 0, stream>>>(qkv_bf, o_bf);

  gemm_bt<D_MODEL, true><<<dim3(M_PAD / 128, D_MODEL / 128), 256, 0, stream>>>(
      o_bf, wout_bf, b_out, nullptr, out, x);
}

// Round 2
// 379.394 us; speedup vs baseline: 3.7568x; 3.7568x over previous
//
#include <hip/hip_runtime.h>
#include <hip/hip_bf16.h>
#include <stdint.h>

#define D_MODEL 1024
#define QKV_LD  3072
#define N_TOT   9860
#define M_PAD   9984   // 78*128
#define LN_EPS  1e-5f

typedef __bf16 bf16_t;
typedef __bf16 bf16x8 __attribute__((ext_vector_type(8)));
typedef float  f32x4  __attribute__((ext_vector_type(4)));

__device__ inline unsigned short f2bf(float f) {
  __bf16 h = (__bf16)f;
  return __builtin_bit_cast(unsigned short, h);
}

// ---------------- weight f32 -> bf16 ----------------
__global__ __launch_bounds__(256) void cvt_f32_bf16(const float* __restrict__ src,
                                                    bf16_t* __restrict__ dst, int n4) {
  int i = blockIdx.x * 256 + threadIdx.x;
  if (i < n4) {
    float4 v = ((const float4*)src)[i];
    ((ushort4*)dst)[i] = make_ushort4(f2bf(v.x), f2bf(v.y), f2bf(v.z), f2bf(v.w));
  }
}

// ---------------- LayerNorm: x f32 -> h bf16 (pads zeroed) ----------------
__global__ __launch_bounds__(256) void ln_kernel(const float* __restrict__ x,
                                                 const float* __restrict__ g,
                                                 const float* __restrict__ b,
                                                 bf16_t* __restrict__ hout,
                                                 bf16_t* __restrict__ opad) {
  int row = blockIdx.x;
  int t = threadIdx.x;
  if (row >= N_TOT) {
    ((ushort4*)(hout + (size_t)row * D_MODEL))[t] = make_ushort4(0, 0, 0, 0);
    ((ushort4*)(opad + (size_t)row * D_MODEL))[t] = make_ushort4(0, 0, 0, 0);
    return;
  }
  float4 v = ((const float4*)(x + (size_t)row * D_MODEL))[t];
  float s  = v.x + v.y + v.z + v.w;
  float sq = v.x * v.x + v.y * v.y + v.z * v.z + v.w * v.w;
  #pragma unroll
  for (int off = 1; off < 64; off <<= 1) {
    s  += __shfl_xor(s, off);
    sq += __shfl_xor(sq, off);
  }
  __shared__ float ss[4], ssq[4];
  int wid = t >> 6;
  if ((t & 63) == 0) { ss[wid] = s; ssq[wid] = sq; }
  __syncthreads();
  s  = ss[0] + ss[1] + ss[2] + ss[3];
  sq = ssq[0] + ssq[1] + ssq[2] + ssq[3];
  float mu  = s * (1.0f / 1024.0f);
  float var = sq * (1.0f / 1024.0f) - mu * mu;
  float rs  = rsqrtf(var + LN_EPS);
  float4 gv = ((const float4*)g)[t];
  float4 bv = ((const float4*)b)[t];
  ushort4 o;
  o.x = f2bf((v.x - mu) * rs * gv.x + bv.x);
  o.y = f2bf((v.y - mu) * rs * gv.y + bv.y);
  o.z = f2bf((v.z - mu) * rs * gv.z + bv.z);
  o.w = f2bf((v.w - mu) * rs * gv.w + bv.w);
  ((ushort4*)(hout + (size_t)row * D_MODEL))[t] = o;
}

// ---------------- GEMM: C[M][NC] = A[M][K] * B[NC][K]^T (+bias, +resid) ----------------
template<int NCOLS, bool FINAL>
__global__ __launch_bounds__(256) void gemm_bt(const bf16_t* __restrict__ A,
                                               const bf16_t* __restrict__ B,
                                               const float* __restrict__ bias,
                                               bf16_t* __restrict__ Cbf,
                                               float* __restrict__ Cf,
                                               const float* __restrict__ resid) {
  constexpr int K = 1024;
  const int tileM = blockIdx.x;
  const int tileN = blockIdx.y;
  const int t = threadIdx.x;
  const int lane = t & 63, wid = t >> 6;
  const int wr = wid >> 1, wc = wid & 1;

  __shared__ bf16_t Asm[128 * 64];
  __shared__ bf16_t Bsm[128 * 64];

  f32x4 acc[4][4];
  #pragma unroll
  for (int m = 0; m < 4; ++m)
    #pragma unroll
    for (int n = 0; n < 4; ++n)
      acc[m][n] = f32x4{0.f, 0.f, 0.f, 0.f};

  const int rowA0 = tileM * 128, rowB0 = tileN * 128;

  for (int kt = 0; kt < K / 64; ++kt) {
    __syncthreads();
    const int k0 = kt * 64;
    #pragma unroll
    for (int i = 0; i < 4; ++i) {
      int idx = i * 256 + t;
      int r = idx >> 3, c = idx & 7;
      int sw = (c ^ (r & 7)) * 16;
      int4 va = *(const int4*)(A + (size_t)(rowA0 + r) * K + k0 + c * 8);
      *(int4*)((char*)Asm + r * 128 + sw) = va;
      int4 vb = *(const int4*)(B + (size_t)(rowB0 + r) * K + k0 + c * 8);
      *(int4*)((char*)Bsm + r * 128 + sw) = vb;
    }
    __syncthreads();
    #pragma unroll
    for (int ks = 0; ks < 2; ++ks) {
      bf16x8 af[4], bfr[4];
      #pragma unroll
      for (int m = 0; m < 4; ++m) {
        int r = wr * 64 + m * 16 + (lane & 15);
        int c = ks * 4 + (lane >> 4);
        af[m] = *(const bf16x8*)((const char*)Asm + r * 128 + ((c ^ (r & 7)) * 16));
      }
      #pragma unroll
      for (int n = 0; n < 4; ++n) {
        int r = wc * 64 + n * 16 + (lane & 15);
        int c = ks * 4 + (lane >> 4);
        bfr[n] = *(const bf16x8*)((const char*)Bsm + r * 128 + ((c ^ (r & 7)) * 16));
      }
      #pragma unroll
      for (int m = 0; m < 4; ++m)
        #pragma unroll
        for (int n = 0; n < 4; ++n)
          acc[m][n] = __builtin_amdgcn_mfma_f32_16x16x32_bf16(af[m], bfr[n], acc[m][n], 0, 0, 0);
    }
  }

  #pragma unroll
  for (int m = 0; m < 4; ++m) {
    int rb = tileM * 128 + wr * 64 + m * 16 + ((lane >> 4) << 2);
    #pragma unroll
    for (int n = 0; n < 4; ++n) {
      int cb = tileN * 128 + wc * 64 + n * 16 + (lane & 15);
      float bv = bias[cb];
      #pragma unroll
      for (int j = 0; j < 4; ++j) {
        int grow = rb + j;
        float val = acc[m][n][j] + bv;
        if constexpr (FINAL) {
          if (grow < N_TOT) {
            size_t idx = (size_t)grow * NCOLS + cb;
            Cf[idx] = resid[idx] + val;
          }
        } else {
          Cbf[(size_t)grow * NCOLS + cb] = (bf16_t)val;
        }
      }
    }
  }
}

// ---------------- V transpose: qkv[:,2048+c] -> vt[c][token] ----------------
__global__ __launch_bounds__(256) void transpose_v(const bf16_t* __restrict__ qkv,
                                                   bf16_t* __restrict__ vt) {
  __shared__ bf16_t tile[64][72];   // 144B rows: 16B-aligned
  const int t = threadIdx.x;
  const int n0 = blockIdx.x * 64, c0 = blockIdx.y * 64;
  #pragma unroll
  for (int it = 0; it < 2; ++it) {
    int idx = it * 256 + t;
    int row = idx >> 3, ch = idx & 7;
    bf16x8 v = *(const bf16x8*)(qkv + (size_t)(n0 + row) * QKV_LD + 2048 + c0 + ch * 8);
    *(bf16x8*)(&tile[row][ch * 8]) = v;
  }
  __syncthreads();
  #pragma unroll
  for (int it = 0; it < 2; ++it) {
    int idx = it * 256 + t;
    int crow = idx >> 3, ng = idx & 7;
    bf16x8 o;
    #pragma unroll
    for (int i = 0; i < 8; ++i) o[i] = tile[ng * 8 + i][crow];
    *(bf16x8*)(vt + (size_t)(c0 + crow) * M_PAD + n0 + ng * 8) = o;
  }
}

// ---------------- attention: MFMA flash, 4 waves x 16 qrows, KV tile 64 ----------------
__global__ __launch_bounds__(256) void attn_mfma(const bf16_t* __restrict__ qkv,
                                                 const bf16_t* __restrict__ vt,
                                                 bf16_t* __restrict__ obuf) {
  static const int off_[9] = {0, 1536, 2560, 3960, 4860, 6060, 7360, 8860, 9860};
  static const int ts_[9]  = {0, 24, 40, 62, 77, 96, 117, 141, 157};
  const int tt = blockIdx.x;
  const int h  = blockIdx.y;
  int b = 0;
  #pragma unroll
  for (int i = 1; i < 8; ++i) b += (tt >= ts_[i]);
  const int L    = off_[b + 1] - off_[b];
  const int q0   = (tt - ts_[b]) * 64;
  const int tok0 = off_[b] + q0;
  const int nq   = (L - q0 < 64) ? (L - q0) : 64;

  const int t = threadIdx.x;
  const int lane = t & 63, w = t >> 6;
  const int lg = lane >> 4, lr = lane & 15;

  __shared__ char Ks[8192];   // [64 keys][64 dims] bf16, XOR-swizzled
  __shared__ char Vs[8192];   // [64 dims][64 keys] bf16 (V^T), XOR-swizzled
  __shared__ char Ps[8192];   // [64 qrows][64 keys] bf16, XOR-swizzled

  // Q fragments (A operand), pre-scaled by 1/sqrt(64) = 0.125 (exact in bf16)
  bf16x8 qf[2];
  {
    const bf16_t* qp = qkv + (size_t)(tok0 + w * 16 + lr) * QKV_LD + h * 64;
    #pragma unroll
    for (int ks = 0; ks < 2; ++ks) {
      bf16x8 v = *(const bf16x8*)(qp + ks * 32 + lg * 8);
      #pragma unroll
      for (int i = 0; i < 8; ++i) v[i] = (__bf16)((float)v[i] * 0.125f);
      qf[ks] = v;
    }
  }

  f32x4 accO[4];
  #pragma unroll
  for (int n = 0; n < 4; ++n) accO[n] = f32x4{0.f, 0.f, 0.f, 0.f};
  float m_run[4] = {-INFINITY, -INFINITY, -INFINITY, -INFINITY};
  float l_run[4] = {0.f, 0.f, 0.f, 0.f};

  const int kbase = off_[b];
  for (int kv0 = 0; kv0 < L; kv0 += 64) {
    const int nk = (L - kv0 < 64) ? (L - kv0) : 64;
    __syncthreads();   // previous tile's LDS reads done
    // cooperative staging: K rows (swizzled) + V^T rows (swizzled)
    #pragma unroll
    for (int it = 0; it < 2; ++it) {
      int idx = it * 256 + t;
      int row = idx >> 3, ch = idx & 7;
      int4 kv = *(const int4*)(qkv + (size_t)(kbase + kv0 + row) * QKV_LD + 1024 + h * 64 + ch * 8);
      *(int4*)(Ks + row * 128 + ((ch ^ (row & 7)) * 16)) = kv;
      const bf16_t* vp = vt + (size_t)(h * 64 + row) * M_PAD + kbase + kv0 + ch * 8;
      int2 v0 = *(const int2*)vp;          // 8B-aligned loads (off[b] % 4 == 0)
      int2 v1 = *(const int2*)(vp + 4);
      int4 vv; vv.x = v0.x; vv.y = v0.y; vv.z = v1.x; vv.w = v1.y;
      *(int4*)(Vs + row * 128 + ((ch ^ (row & 7)) * 16)) = vv;
    }
    __syncthreads();

    // S = Q*K^T (per-wave 16x64)
    f32x4 accS[4];
    #pragma unroll
    for (int n = 0; n < 4; ++n) accS[n] = f32x4{0.f, 0.f, 0.f, 0.f};
    #pragma unroll
    for (int ks = 0; ks < 2; ++ks) {
      #pragma unroll
      for (int n = 0; n < 4; ++n) {
        int key = n * 16 + lr;
        bf16x8 kf = *(const bf16x8*)(Ks + key * 128 + (((ks * 4 + lg) ^ (key & 7)) * 16));
        accS[n] = __builtin_amdgcn_mfma_f32_16x16x32_bf16(qf[ks], kf, accS[n], 0, 0, 0);
      }
    }

    // online softmax; lane owns rows qrow=(lg*4+j), cols key=16n+lr
    #pragma unroll
    for (int j = 0; j < 4; ++j) {
      float mx = -INFINITY;
      #pragma unroll
      for (int n = 0; n < 4; ++n) {
        float s = (n * 16 + lr < nk) ? accS[n][j] : -INFINITY;
        accS[n][j] = s;
        mx = fmaxf(mx, s);
      }
      mx = fmaxf(mx, __shfl_xor(mx, 1));
      mx = fmaxf(mx, __shfl_xor(mx, 2));
      mx = fmaxf(mx, __shfl_xor(mx, 4));
      mx = fmaxf(mx, __shfl_xor(mx, 8));
      float mnew = fmaxf(m_run[j], mx);
      float scl = __expf(m_run[j] - mnew);
      int qrow = w * 16 + lg * 4 + j;
      float sum = 0.f;
      #pragma unroll
      for (int n = 0; n < 4; ++n) {
        float pv = __expf(accS[n][j] - mnew);   // masked -> exp(-inf)=0
        sum += pv;
        *(unsigned short*)(Ps + qrow * 128 + (((2 * n + (lr >> 3)) ^ (qrow & 7)) * 16)
                           + (lr & 7) * 2) = f2bf(pv);
      }
      sum += __shfl_xor(sum, 1);
      sum += __shfl_xor(sum, 2);
      sum += __shfl_xor(sum, 4);
      sum += __shfl_xor(sum, 8);
      l_run[j] = l_run[j] * scl + sum;
      m_run[j] = mnew;
      #pragma unroll
      for (int n = 0; n < 4; ++n) accO[n][j] *= scl;
    }

    // O += P * V   (P from LDS as A-frag; V^T rows give B-frag)
    #pragma unroll
    for (int ks = 0; ks < 2; ++ks) {
      int prow = w * 16 + lr;
      bf16x8 pa = *(const bf16x8*)(Ps + prow * 128 + (((ks * 4 + lg) ^ (prow & 7)) * 16));
      #pragma unroll
      for (int n = 0; n < 4; ++n) {
        int dim = n * 16 + lr;
        bf16x8 vf = *(const bf16x8*)(Vs + dim * 128 + (((ks * 4 + lg) ^ (dim & 7)) * 16));
        accO[n] = __builtin_amdgcn_mfma_f32_16x16x32_bf16(pa, vf, accO[n], 0, 0, 0);
      }
    }
  }

  #pragma unroll
  for (int j = 0; j < 4; ++j) {
    int qlocal = w * 16 + lg * 4 + j;
    if (qlocal < nq) {
      float inv = 1.f / l_run[j];
      bf16_t* op = obuf + (size_t)(tok0 + qlocal) * D_MODEL + h * 64;
      #pragma unroll
      for (int n = 0; n < 4; ++n)
        op[n * 16 + lr] = (bf16_t)(accO[n][j] * inv);
    }
  }
}

// ---------------- launcher ----------------
extern "C" void kernel_launch(void* const* d_in, const int* in_sizes, int n_in,
                              void* d_out, int out_size, void* d_ws, size_t ws_size,
                              hipStream_t stream) {
  const float* x     = (const float*)d_in[0];
  const float* w_in  = (const float*)d_in[2];
  const float* b_in  = (const float*)d_in[3];
  const float* w_out = (const float*)d_in[4];
  const float* b_out = (const float*)d_in[5];
  const float* ln_g  = (const float*)d_in[6];
  const float* ln_b  = (const float*)d_in[7];
  float* out = (float*)d_out;

  char* ws = (char*)d_ws;
  const size_t SZ_H   = (size_t)M_PAD * D_MODEL * 2;
  const size_t SZ_QKV = (size_t)M_PAD * QKV_LD * 2;
  const size_t SZ_O   = SZ_H;
  const size_t SZ_WIN = (size_t)QKV_LD * D_MODEL * 2;
  const size_t SZ_WO  = (size_t)D_MODEL * D_MODEL * 2;
  if (ws_size < SZ_H + SZ_QKV + SZ_O + SZ_WIN + SZ_WO) return;

  bf16_t* h_bf    = (bf16_t*)ws;                         // reused as Vt after QKV GEMM
  bf16_t* qkv_bf  = (bf16_t*)(ws + SZ_H);
  bf16_t* o_bf    = (bf16_t*)(ws + SZ_H + SZ_QKV);
  bf16_t* win_bf  = (bf16_t*)(ws + SZ_H + SZ_QKV + SZ_O);
  bf16_t* wout_bf = (bf16_t*)(ws + SZ_H + SZ_QKV + SZ_O + SZ_WIN);

  cvt_f32_bf16<<<(QKV_LD * D_MODEL / 4) / 256, 256, 0, stream>>>(w_in, win_bf, QKV_LD * D_MODEL / 4);
  cvt_f32_bf16<<<(D_MODEL * D_MODEL / 4) / 256, 256, 0, stream>>>(w_out, wout_bf, D_MODEL * D_MODEL / 4);

  ln_kernel<<<M_PAD, 256, 0, stream>>>(x, ln_g, ln_b, h_bf, o_bf);

  gemm_bt<QKV_LD, false><<<dim3(M_PAD / 128, QKV_LD / 128), 256, 0, stream>>>(
      h_bf, win_bf, b_in, qkv_bf, nullptr, nullptr);

  bf16_t* vt = h_bf;   // h is dead after the QKV GEMM
  transpose_v<<<dim3(M_PAD / 64, D_MODEL / 64), 256, 0, stream>>>(qkv_bf, vt);

  attn_mfma<<<dim3(157, 16), 256, 0, stream>>>(qkv_bf, vt, o_bf);

  gemm_bt<D_MODEL, true><<<dim3(M_PAD / 128, D_MODEL / 128), 256, 0, stream>>>(
      o_bf, wout_bf, b_out, nullptr, out, x);
}